// Round 8
// baseline (197.702 us; speedup 1.0000x reference)
//
#include <hip/hip_runtime.h>
#include <stdint.h>
#include <stddef.h>

typedef int v4i __attribute__((ext_vector_type(4)));

#define GLOAD_LDS16(g, l) __builtin_amdgcn_global_load_lds( \
    (const __attribute__((address_space(1))) void*)(g),     \
    (__attribute__((address_space(3))) void*)(l), 16, 0, 0)

// ---------------------------------------------------------------------------
// Quantize rows of length 2048: one wave per row, 4 rows per 256-thread block.
// scale = max(amax/127, floorv); q = clip(rint(v/scale), -128, 127)
// ---------------------------------------------------------------------------
__device__ __forceinline__ int pack4(float4 f, float s) {
    int a = (int)rintf(f.x / s); a = a < -128 ? -128 : (a > 127 ? 127 : a);
    int b = (int)rintf(f.y / s); b = b < -128 ? -128 : (b > 127 ? 127 : b);
    int c = (int)rintf(f.z / s); c = c < -128 ? -128 : (c > 127 ? 127 : c);
    int d = (int)rintf(f.w / s); d = d < -128 ? -128 : (d > 127 ? 127 : d);
    return (a & 255) | ((b & 255) << 8) | ((c & 255) << 16) | ((d & 255) << 24);
}

__global__ __launch_bounds__(256) void quant_rows_2048(
    const float* __restrict__ in, signed char* __restrict__ q,
    float* __restrict__ scales, float floorv)
{
    const int lane = threadIdx.x & 63;
    const int row  = blockIdx.x * 4 + (threadIdx.x >> 6);
    const float* rp = in + (size_t)row * 2048;

    float4 v[8];
#pragma unroll
    for (int j = 0; j < 2; ++j) {
        const float4* p = (const float4*)(rp + j * 1024 + lane * 16);
#pragma unroll
        for (int i = 0; i < 4; ++i) v[j * 4 + i] = p[i];
    }
    float am = 0.0f;
#pragma unroll
    for (int i = 0; i < 8; ++i) {
        am = fmaxf(am, fabsf(v[i].x));
        am = fmaxf(am, fabsf(v[i].y));
        am = fmaxf(am, fabsf(v[i].z));
        am = fmaxf(am, fabsf(v[i].w));
    }
#pragma unroll
    for (int off = 32; off; off >>= 1) am = fmaxf(am, __shfl_xor(am, off));
    const float s = fmaxf(am / 127.0f, floorv);

#pragma unroll
    for (int j = 0; j < 2; ++j) {
        int4 pk;
        pk.x = pack4(v[j * 4 + 0], s);
        pk.y = pack4(v[j * 4 + 1], s);
        pk.z = pack4(v[j * 4 + 2], s);
        pk.w = pack4(v[j * 4 + 3], s);
        *(int4*)(q + (size_t)row * 2048 + j * 1024 + lane * 16) = pk;
    }
    if (lane == 0) scales[row] = s;
}

// ---------------------------------------------------------------------------
// int8 GEMM — B-in-registers structure (LDS pipe was the R7 bottleneck):
// 128x256 tile, BK=64, 512 thr = 8 waves (2M x 4N), per-wave 64x64 via
// 4x4 frags of mfma_i32_16x16x64_i8.
//   A: LDS double-buffer (2 x 8KB = 16 KB total), global_load_lds staging,
//      chunk-XOR swizzle (2-way bank aliasing = free).
//   B: global -> REGISTER, MFMA-layout-native (lane l reads 16B at
//      wq[col+(l&15)][kt*64+(l>>4)*16]); double-buffered bc/bn, consumed
//      per-wave via the compiler's vmcnt — no barrier, no LDS traffic.
//      wq = 4MB, XCD-L2-resident (XCD swizzle groups same-column blocks).
// Per tile: {stage A(t+1); issue 4 B-loads(t+1); 4 ds_read A frags;
//            16 MFMA on bc; __syncthreads; bc <- bn}.
// Per-CU pipe balance per block-tile pair: MFMA 1306 cyc/SIMD (binding),
// LDS ~900, L2-B ~1090 — MFMA-bound by design.
// ---------------------------------------------------------------------------
__global__ __launch_bounds__(512, 4) void gemm_i8_breg(
    const signed char* __restrict__ xq, const signed char* __restrict__ wq,
    const float* __restrict__ xs, const float* __restrict__ ws,
    const float* __restrict__ bias, float* __restrict__ out, int K)
{
    __shared__ __align__(16) signed char lds[16384]; // A[2][8192]

    const int tid  = threadIdx.x;
    const int lane = tid & 63;
    const int wid  = tid >> 6;
    const int wm   = wid >> 2;        // 0..1
    const int wn   = wid & 3;         // 0..3

    const int nwg  = gridDim.x * gridDim.y;
    int orig = blockIdx.y * gridDim.x + blockIdx.x;
    int swz  = ((nwg & 7) == 0) ? ((orig & 7) * (nwg >> 3) + (orig >> 3)) : orig;
    const int brow = (swz / gridDim.x) * 128;
    const int bcol = (swz % gridDim.x) * 256;

    // A staging: thread -> (row = tid>>2 in 0..127, chunk = tid&3), swizzled src
    const int gch  = (((tid & 3) ^ ((tid >> 3) & 3)) << 4);
    const int lofs = tid << 4;
    const signed char* gA = xq + (size_t)(brow + (tid >> 2)) * K;

#define ST_A(tt, bb) GLOAD_LDS16(gA + (size_t)(tt) * 64 + gch, \
                                 lds + ((bb) ? 8192 : 0) + lofs)

    const int rl   = lane & 15;
    const int ko   = lane >> 4;
    const int slot = ((ko ^ ((rl >> 1) & 3)) << 4);

#define FRAG_A(bb, r) (*(const v4i*)(lds + (((bb) ? 8192 : 0) + (r) * 64 + slot)))

    // B: direct global->register, MFMA-native layout
    const signed char* gB = wq + (size_t)(bcol + wn * 64 + rl) * K + (ko << 4);
    const size_t bfs = (size_t)16 * K;   // frag stride (16 cols)

    v4i acc[4][4] = {};
    const int ar = wm * 64 + rl;

    // ---- prologue: stage A(0); load B(0)
    ST_A(0, 0);
    v4i bc0 = *(const v4i*)(gB);
    v4i bc1 = *(const v4i*)(gB + bfs);
    v4i bc2 = *(const v4i*)(gB + 2 * bfs);
    v4i bc3 = *(const v4i*)(gB + 3 * bfs);
    __syncthreads();

    const int NT = K >> 6;   // 32
    for (int t = 0; t < NT; ++t) {
        const int buf = t & 1;
        v4i bn0, bn1, bn2, bn3;
        if (t + 1 < NT) {
            ST_A(t + 1, buf ^ 1);
            const signed char* gBt = gB + (size_t)(t + 1) * 64;
            bn0 = *(const v4i*)(gBt);
            bn1 = *(const v4i*)(gBt + bfs);
            bn2 = *(const v4i*)(gBt + 2 * bfs);
            bn3 = *(const v4i*)(gBt + 3 * bfs);
        }
        v4i af[4];
#pragma unroll
        for (int m = 0; m < 4; ++m) af[m] = FRAG_A(buf, ar + m * 16);
#pragma unroll
        for (int m = 0; m < 4; ++m) {
            acc[m][0] = __builtin_amdgcn_mfma_i32_16x16x64_i8(af[m], bc0, acc[m][0], 0, 0, 0);
            acc[m][1] = __builtin_amdgcn_mfma_i32_16x16x64_i8(af[m], bc1, acc[m][1], 0, 0, 0);
            acc[m][2] = __builtin_amdgcn_mfma_i32_16x16x64_i8(af[m], bc2, acc[m][2], 0, 0, 0);
            acc[m][3] = __builtin_amdgcn_mfma_i32_16x16x64_i8(af[m], bc3, acc[m][3], 0, 0, 0);
        }
        __syncthreads();
        if (t + 1 < NT) { bc0 = bn0; bc1 = bn1; bc2 = bn2; bc3 = bn3; }
    }

    // ---- epilogue: C/D layout col = lane&15, row = (lane>>4)*4 + j
    const int rg = lane >> 4;
#pragma unroll
    for (int n = 0; n < 4; ++n) {
        const int col = bcol + wn * 64 + n * 16 + rl;
        const float wsc = ws[col];
        const float bv  = bias[col];
#pragma unroll
        for (int m = 0; m < 4; ++m) {
#pragma unroll
            for (int j = 0; j < 4; ++j) {
                const int row = brow + wm * 64 + m * 16 + rg * 4 + j;
                out[(size_t)row * 2048 + col] =
                    (float)acc[m][n][j] * xs[row] * wsc + bv;
            }
        }
    }
#undef ST_A
#undef FRAG_A
}

// ---------------------------------------------------------------------------
extern "C" void kernel_launch(void* const* d_in, const int* in_sizes, int n_in,
                              void* d_out, int out_size, void* d_ws, size_t ws_size,
                              hipStream_t stream) {
    const float* x    = (const float*)d_in[0];   // [B,N,D] = [4,4096,2048]
    const float* w    = (const float*)d_in[1];   // [O,D]   = [2048,2048]
    const float* bias = (const float*)d_in[2];   // [O]
    float* out = (float*)d_out;

    const int D = 2048;
    const int O = in_sizes[2];                   // 2048
    const int M = in_sizes[0] / D;               // 16384

    char* wsb = (char*)d_ws;
    signed char* xq  = (signed char*)wsb;
    signed char* wqp = (signed char*)(wsb + (size_t)M * D);
    float* xs  = (float*)(wsb + (size_t)M * D + (size_t)O * D);
    float* wsc = (float*)(wsb + (size_t)M * D + (size_t)O * D + (size_t)M * 4);

    quant_rows_2048<<<M / 4, 256, 0, stream>>>(x, xq, xs, 1e-12f);
    quant_rows_2048<<<O / 4, 256, 0, stream>>>(w, wqp, wsc, 1e-8f / 127.0f);

    dim3 grid(O / 256, M / 128);   // (8, 128) = 1024 blocks, %8 == 0
    gemm_i8_breg<<<grid, 512, 0, stream>>>(xq, wqp, xs, wsc, bias, out, D);
}

// Round 9
// 126.424 us; speedup vs baseline: 1.5638x; 1.5638x over previous
//
#include <hip/hip_runtime.h>
#include <stdint.h>
#include <stddef.h>

typedef int v4i __attribute__((ext_vector_type(4)));

#define GLOAD_LDS16(g, l) __builtin_amdgcn_global_load_lds( \
    (const __attribute__((address_space(1))) void*)(g),     \
    (__attribute__((address_space(3))) void*)(l), 16, 0, 0)

// ---------------------------------------------------------------------------
// Quantize rows of length 2048: one wave per row, 4 rows per 256-thread block.
// scale = max(amax/127, floorv); q = clip(rint(v/scale), -128, 127)
// ---------------------------------------------------------------------------
__device__ __forceinline__ int pack4(float4 f, float s) {
    int a = (int)rintf(f.x / s); a = a < -128 ? -128 : (a > 127 ? 127 : a);
    int b = (int)rintf(f.y / s); b = b < -128 ? -128 : (b > 127 ? 127 : b);
    int c = (int)rintf(f.z / s); c = c < -128 ? -128 : (c > 127 ? 127 : c);
    int d = (int)rintf(f.w / s); d = d < -128 ? -128 : (d > 127 ? 127 : d);
    return (a & 255) | ((b & 255) << 8) | ((c & 255) << 16) | ((d & 255) << 24);
}

__global__ __launch_bounds__(256) void quant_rows_2048(
    const float* __restrict__ in, signed char* __restrict__ q,
    float* __restrict__ scales, float floorv)
{
    const int lane = threadIdx.x & 63;
    const int row  = blockIdx.x * 4 + (threadIdx.x >> 6);
    const float* rp = in + (size_t)row * 2048;

    float4 v[8];
#pragma unroll
    for (int j = 0; j < 2; ++j) {
        const float4* p = (const float4*)(rp + j * 1024 + lane * 16);
#pragma unroll
        for (int i = 0; i < 4; ++i) v[j * 4 + i] = p[i];
    }
    float am = 0.0f;
#pragma unroll
    for (int i = 0; i < 8; ++i) {
        am = fmaxf(am, fabsf(v[i].x));
        am = fmaxf(am, fabsf(v[i].y));
        am = fmaxf(am, fabsf(v[i].z));
        am = fmaxf(am, fabsf(v[i].w));
    }
#pragma unroll
    for (int off = 32; off; off >>= 1) am = fmaxf(am, __shfl_xor(am, off));
    const float s = fmaxf(am / 127.0f, floorv);

#pragma unroll
    for (int j = 0; j < 2; ++j) {
        int4 pk;
        pk.x = pack4(v[j * 4 + 0], s);
        pk.y = pack4(v[j * 4 + 1], s);
        pk.z = pack4(v[j * 4 + 2], s);
        pk.w = pack4(v[j * 4 + 3], s);
        *(int4*)(q + (size_t)row * 2048 + j * 1024 + lane * 16) = pk;
    }
    if (lane == 0) scales[row] = s;
}

// ---------------------------------------------------------------------------
// int8 GEMM — R7 structure (2 blocks/CU, proven best) + counted-vmcnt ring:
// 128x256 tile, BK=64, 512 thr = 8 waves (2M x 4N), per-wave 64x64 via
// 4x4 frags of mfma_i32_16x16x64_i8 (acc = 64 regs, VGPR_Count 64 in R7).
// LDS ring-3 of (A 8KB + B 16KB) = 72 KB -> 2 blocks/CU. Prefetch distance 2.
// Per tile t: {stage t+2 -> (t+2)%3 (3 gloads); 8 ds_read frags of t%3;
//   16 MFMA (compiler lgkm waits); lgkmcnt(0)+vmcnt(3) counted; raw s_barrier}
// vmcnt never drains to 0 mid-loop (T4) -> one tile of loads always crosses
// the barrier; lgkmcnt(0) pre-barrier makes the (t+2)%3 == (t-1)%3 WAR
// race architecturally impossible (all reads RETURNED before any overwrite).
// Swizzle: slot s of row r holds global chunk s ^ ((r>>1)&3): 2-way = free.
// ---------------------------------------------------------------------------
__global__ __launch_bounds__(512, 4) void gemm_i8_ring(
    const signed char* __restrict__ xq, const signed char* __restrict__ wq,
    const float* __restrict__ xs, const float* __restrict__ ws,
    const float* __restrict__ bias, float* __restrict__ out, int K)
{
    __shared__ __align__(16) signed char lds[73728]; // 3 x (A 8K | B 16K)

    const int tid  = threadIdx.x;
    const int lane = tid & 63;
    const int wid  = tid >> 6;
    const int wm   = wid >> 2;        // 0..1
    const int wn   = wid & 3;         // 0..3

    const int nwg  = gridDim.x * gridDim.y;
    int orig = blockIdx.y * gridDim.x + blockIdx.x;
    int swz  = ((nwg & 7) == 0) ? ((orig & 7) * (nwg >> 3) + (orig >> 3)) : orig;
    const int brow = (swz / gridDim.x) * 128;
    const int bcol = (swz % gridDim.x) * 256;

    // staging: thread -> (row = tid>>2 in 0..127, chunk = tid&3), swizzled src
    const int gch  = (((tid & 3) ^ ((tid >> 3) & 3)) << 4);
    const int lofs = tid << 4;
    const signed char* gA  = xq + (size_t)(brow + (tid >> 2)) * K;
    const signed char* gB0 = wq + (size_t)(bcol + (tid >> 2)) * K;
    const signed char* gB1 = wq + (size_t)(bcol + 128 + (tid >> 2)) * K;

#define BUFOFF(bb) ((bb) * 24576)
#define ST3(tt, bb) do {                                                         \
    GLOAD_LDS16(gA  + (size_t)(tt) * 64 + gch, lds + BUFOFF(bb) + lofs);         \
    GLOAD_LDS16(gB0 + (size_t)(tt) * 64 + gch, lds + BUFOFF(bb) + 8192 + lofs);  \
    GLOAD_LDS16(gB1 + (size_t)(tt) * 64 + gch, lds + BUFOFF(bb) + 16384 + lofs); \
} while (0)

    const int rl   = lane & 15;
    const int ko   = lane >> 4;
    const int slot = ((ko ^ ((rl >> 1) & 3)) << 4);

#define FRAG_A(bb, r) (*(const v4i*)(lds + BUFOFF(bb) + (r) * 64 + slot))
#define FRAG_B(bb, r) (*(const v4i*)(lds + BUFOFF(bb) + 8192 + (r) * 64 + slot))

    v4i acc[4][4] = {};
    const int ar = wm * 64 + rl;
    const int br = wn * 64 + rl;

    // ---- prologue: stage tiles 0,1; wait tile 0 (counted), barrier
    ST3(0, 0);
    ST3(1, 1);
    asm volatile("s_waitcnt vmcnt(3)" ::: "memory");
    __builtin_amdgcn_s_barrier();

    const int NT = K >> 6;   // 32
    for (int t = 0; t < NT; ++t) {
        const int buf = t % 3;
        if (t + 2 < NT) ST3(t + 2, (t + 2) % 3);

        v4i af[4], bf[4];
#pragma unroll
        for (int m = 0; m < 4; ++m) af[m] = FRAG_A(buf, ar + m * 16);
#pragma unroll
        for (int n = 0; n < 4; ++n) bf[n] = FRAG_B(buf, br + n * 16);
        __builtin_amdgcn_s_setprio(1);
#pragma unroll
        for (int m = 0; m < 4; ++m)
#pragma unroll
            for (int n = 0; n < 4; ++n)
                acc[m][n] = __builtin_amdgcn_mfma_i32_16x16x64_i8(
                    af[m], bf[n], acc[m][n], 0, 0, 0);
        __builtin_amdgcn_s_setprio(0);

        if (t + 2 < NT) {
            // t+1 resident (its 3 loads drained), t+2's 3 stay in flight
            asm volatile("s_waitcnt vmcnt(3) lgkmcnt(0)" ::: "memory");
            __builtin_amdgcn_s_barrier();
        } else if (t + 2 == NT) {
            // drain the last staged tile (NT-1)
            asm volatile("s_waitcnt vmcnt(0) lgkmcnt(0)" ::: "memory");
            __builtin_amdgcn_s_barrier();
        }
        // t == NT-1: no further loads, fall through to epilogue
    }

    // ---- epilogue: C/D layout col = lane&15, row = (lane>>4)*4 + j
    const int rg = lane >> 4;
#pragma unroll
    for (int n = 0; n < 4; ++n) {
        const int col = bcol + wn * 64 + n * 16 + rl;
        const float wsc = ws[col];
        const float bv  = bias[col];
#pragma unroll
        for (int m = 0; m < 4; ++m) {
#pragma unroll
            for (int j = 0; j < 4; ++j) {
                const int row = brow + wm * 64 + m * 16 + rg * 4 + j;
                out[(size_t)row * 2048 + col] =
                    (float)acc[m][n][j] * xs[row] * wsc + bv;
            }
        }
    }
#undef ST3
#undef BUFOFF
#undef FRAG_A
#undef FRAG_B
}

// ---------------------------------------------------------------------------
extern "C" void kernel_launch(void* const* d_in, const int* in_sizes, int n_in,
                              void* d_out, int out_size, void* d_ws, size_t ws_size,
                              hipStream_t stream) {
    const float* x    = (const float*)d_in[0];   // [B,N,D] = [4,4096,2048]
    const float* w    = (const float*)d_in[1];   // [O,D]   = [2048,2048]
    const float* bias = (const float*)d_in[2];   // [O]
    float* out = (float*)d_out;

    const int D = 2048;
    const int O = in_sizes[2];                   // 2048
    const int M = in_sizes[0] / D;               // 16384

    char* wsb = (char*)d_ws;
    signed char* xq  = (signed char*)wsb;
    signed char* wqp = (signed char*)(wsb + (size_t)M * D);
    float* xs  = (float*)(wsb + (size_t)M * D + (size_t)O * D);
    float* wsc = (float*)(wsb + (size_t)M * D + (size_t)O * D + (size_t)M * 4);

    quant_rows_2048<<<M / 4, 256, 0, stream>>>(x, xq, xs, 1e-12f);
    quant_rows_2048<<<O / 4, 256, 0, stream>>>(w, wqp, wsc, 1e-8f / 127.0f);

    dim3 grid(O / 256, M / 128);   // (8, 128) = 1024 blocks, %8 == 0
    gemm_i8_ring<<<grid, 512, 0, stream>>>(xq, wqp, xs, wsc, bias, out, D);
}

// Round 10
// 124.074 us; speedup vs baseline: 1.5934x; 1.0189x over previous
//
#include <hip/hip_runtime.h>
#include <stdint.h>
#include <stddef.h>

typedef int v4i __attribute__((ext_vector_type(4)));

#define GLOAD_LDS16(g, l) __builtin_amdgcn_global_load_lds( \
    (const __attribute__((address_space(1))) void*)(g),     \
    (__attribute__((address_space(3))) void*)(l), 16, 0, 0)

// ---------------------------------------------------------------------------
// Quantize rows of length 2048: one wave per row, 4 rows per 256-thread block.
// scale = max(amax/127, floorv); q = clip(rint(v/scale), -128, 127)
// ---------------------------------------------------------------------------
__device__ __forceinline__ int pack4(float4 f, float s) {
    int a = (int)rintf(f.x / s); a = a < -128 ? -128 : (a > 127 ? 127 : a);
    int b = (int)rintf(f.y / s); b = b < -128 ? -128 : (b > 127 ? 127 : b);
    int c = (int)rintf(f.z / s); c = c < -128 ? -128 : (c > 127 ? 127 : c);
    int d = (int)rintf(f.w / s); d = d < -128 ? -128 : (d > 127 ? 127 : d);
    return (a & 255) | ((b & 255) << 8) | ((c & 255) << 16) | ((d & 255) << 24);
}

__global__ __launch_bounds__(256) void quant_rows_2048(
    const float* __restrict__ in, signed char* __restrict__ q,
    float* __restrict__ scales, float floorv)
{
    const int lane = threadIdx.x & 63;
    const int row  = blockIdx.x * 4 + (threadIdx.x >> 6);
    const float* rp = in + (size_t)row * 2048;

    float4 v[8];
#pragma unroll
    for (int j = 0; j < 2; ++j) {
        const float4* p = (const float4*)(rp + j * 1024 + lane * 16);
#pragma unroll
        for (int i = 0; i < 4; ++i) v[j * 4 + i] = p[i];
    }
    float am = 0.0f;
#pragma unroll
    for (int i = 0; i < 8; ++i) {
        am = fmaxf(am, fabsf(v[i].x));
        am = fmaxf(am, fabsf(v[i].y));
        am = fmaxf(am, fabsf(v[i].z));
        am = fmaxf(am, fabsf(v[i].w));
    }
#pragma unroll
    for (int off = 32; off; off >>= 1) am = fmaxf(am, __shfl_xor(am, off));
    const float s = fmaxf(am / 127.0f, floorv);

#pragma unroll
    for (int j = 0; j < 2; ++j) {
        int4 pk;
        pk.x = pack4(v[j * 4 + 0], s);
        pk.y = pack4(v[j * 4 + 1], s);
        pk.z = pack4(v[j * 4 + 2], s);
        pk.w = pack4(v[j * 4 + 3], s);
        *(int4*)(q + (size_t)row * 2048 + j * 1024 + lane * 16) = pk;
    }
    if (lane == 0) scales[row] = s;
}

// ---------------------------------------------------------------------------
// int8 GEMM — fat-wave variant of R9 (LDS pipe was the binding floor):
// 256x128 block-tile, BK=64, 256 thr = 4 waves (2M x 2N), wave-tile 128x64
// via 8x4 frags of mfma_i32_16x16x64_i8 (acc 128 regs, ~190 total,
// 2 waves/SIMD). flops/LDS-read-byte: 2MN/(M+N) = 85 vs 64 at 64x64 —
// halves LDS-read cycles per flop (12 reads per 32 MFMA vs 8 per 16).
// LDS ring-3 of (A 16K + B 8K) = 72 KB -> 2 blocks/CU (8 waves/CU).
// Sync skeleton identical to R9 (proven): per tile {stage t+2 (6 gloads);
// 12 ds_read frags; 32 MFMA; lgkmcnt(0)+vmcnt(6) counted; raw s_barrier};
// vmcnt never 0 mid-loop; lgkmcnt(0) pre-barrier kills the ring WAR race.
// Swizzle: LDS slot s of row r holds global chunk s ^ ((r>>1)&3) (2-way=free);
// valid for all staging groups since row = 64g + (tid>>2), 64g % 4 == 0.
// ---------------------------------------------------------------------------
__global__ __launch_bounds__(256, 2) void gemm_i8_fat(
    const signed char* __restrict__ xq, const signed char* __restrict__ wq,
    const float* __restrict__ xs, const float* __restrict__ ws,
    const float* __restrict__ bias, float* __restrict__ out, int K)
{
    __shared__ __align__(16) signed char lds[73728]; // 3 x (A 16K | B 8K)

    const int tid  = threadIdx.x;
    const int lane = tid & 63;
    const int wid  = tid >> 6;        // 0..3
    const int wm   = wid >> 1;        // 0..1
    const int wn   = wid & 1;         // 0..1

    const int nwg  = gridDim.x * gridDim.y;
    int orig = blockIdx.y * gridDim.x + blockIdx.x;
    int swz  = ((nwg & 7) == 0) ? ((orig & 7) * (nwg >> 3) + (orig >> 3)) : orig;
    const int brow = (swz / gridDim.x) * 256;
    const int bcol = (swz % gridDim.x) * 128;

    // staging: thread -> (row = g*64 + (tid>>2), chunk = tid&3), swizzled src
    const int gch  = (((tid & 3) ^ ((tid >> 3) & 3)) << 4);
    const signed char* gA = xq + (size_t)(brow + (tid >> 2)) * K;
    const signed char* gB = wq + (size_t)(bcol + (tid >> 2)) * K;

#define BUFOFF(bb) ((bb) * 24576)
#define ST6(tt, bb) do {                                                                   \
    GLOAD_LDS16(gA + (size_t)(tt) * 64 + gch,               lds + BUFOFF(bb) + (tid << 4));            \
    GLOAD_LDS16(gA + (size_t)(64 * K) + (size_t)(tt) * 64 + gch,  lds + BUFOFF(bb) + 4096 + (tid << 4));  \
    GLOAD_LDS16(gA + (size_t)(128 * K) + (size_t)(tt) * 64 + gch, lds + BUFOFF(bb) + 8192 + (tid << 4));  \
    GLOAD_LDS16(gA + (size_t)(192 * K) + (size_t)(tt) * 64 + gch, lds + BUFOFF(bb) + 12288 + (tid << 4)); \
    GLOAD_LDS16(gB + (size_t)(tt) * 64 + gch,               lds + BUFOFF(bb) + 16384 + (tid << 4));    \
    GLOAD_LDS16(gB + (size_t)(64 * K) + (size_t)(tt) * 64 + gch,  lds + BUFOFF(bb) + 20480 + (tid << 4));  \
} while (0)

    const int rl   = lane & 15;
    const int ko   = lane >> 4;
    const int slot = ((ko ^ ((rl >> 1) & 3)) << 4);

#define FRAG_A(bb, r) (*(const v4i*)(lds + BUFOFF(bb) + (r) * 64 + slot))
#define FRAG_B(bb, r) (*(const v4i*)(lds + BUFOFF(bb) + 16384 + (r) * 64 + slot))

    v4i acc[8][4] = {};
    const int ar = wm * 128 + rl;
    const int br = wn * 64 + rl;

    // ---- prologue: stage tiles 0,1; counted wait for tile 0; barrier
    ST6(0, 0);
    ST6(1, 1);
    asm volatile("s_waitcnt vmcnt(6)" ::: "memory");
    __builtin_amdgcn_s_barrier();

    const int NT = K >> 6;   // 32
    for (int t = 0; t < NT; ++t) {
        const int buf = t % 3;
        if (t + 2 < NT) ST6(t + 2, (t + 2) % 3);

        v4i af[8], bf[4];
#pragma unroll
        for (int m = 0; m < 8; ++m) af[m] = FRAG_A(buf, ar + m * 16);
#pragma unroll
        for (int n = 0; n < 4; ++n) bf[n] = FRAG_B(buf, br + n * 16);
        __builtin_amdgcn_s_setprio(1);
#pragma unroll
        for (int m = 0; m < 8; ++m)
#pragma unroll
            for (int n = 0; n < 4; ++n)
                acc[m][n] = __builtin_amdgcn_mfma_i32_16x16x64_i8(
                    af[m], bf[n], acc[m][n], 0, 0, 0);
        __builtin_amdgcn_s_setprio(0);

        if (t + 2 < NT) {
            // t+1 resident (its 6 loads drained), t+2's 6 stay in flight
            asm volatile("s_waitcnt vmcnt(6) lgkmcnt(0)" ::: "memory");
            __builtin_amdgcn_s_barrier();
        } else if (t + 2 == NT) {
            asm volatile("s_waitcnt vmcnt(0) lgkmcnt(0)" ::: "memory");
            __builtin_amdgcn_s_barrier();
        }
        // t == NT-1: no further loads, fall through to epilogue
    }

    // ---- epilogue: C/D layout col = lane&15, row = (lane>>4)*4 + j
    const int rg = lane >> 4;
#pragma unroll
    for (int n = 0; n < 4; ++n) {
        const int col = bcol + wn * 64 + n * 16 + rl;
        const float wsc = ws[col];
        const float bv  = bias[col];
#pragma unroll
        for (int m = 0; m < 8; ++m) {
#pragma unroll
            for (int j = 0; j < 4; ++j) {
                const int row = brow + wm * 128 + m * 16 + rg * 4 + j;
                out[(size_t)row * 2048 + col] =
                    (float)acc[m][n][j] * xs[row] * wsc + bv;
            }
        }
    }
#undef ST6
#undef BUFOFF
#undef FRAG_A
#undef FRAG_B
}

// ---------------------------------------------------------------------------
extern "C" void kernel_launch(void* const* d_in, const int* in_sizes, int n_in,
                              void* d_out, int out_size, void* d_ws, size_t ws_size,
                              hipStream_t stream) {
    const float* x    = (const float*)d_in[0];   // [B,N,D] = [4,4096,2048]
    const float* w    = (const float*)d_in[1];   // [O,D]   = [2048,2048]
    const float* bias = (const float*)d_in[2];   // [O]
    float* out = (float*)d_out;

    const int D = 2048;
    const int O = in_sizes[2];                   // 2048
    const int M = in_sizes[0] / D;               // 16384

    char* wsb = (char*)d_ws;
    signed char* xq  = (signed char*)wsb;
    signed char* wqp = (signed char*)(wsb + (size_t)M * D);
    float* xs  = (float*)(wsb + (size_t)M * D + (size_t)O * D);
    float* wsc = (float*)(wsb + (size_t)M * D + (size_t)O * D + (size_t)M * 4);

    quant_rows_2048<<<M / 4, 256, 0, stream>>>(x, xq, xs, 1e-12f);
    quant_rows_2048<<<O / 4, 256, 0, stream>>>(w, wqp, wsc, 1e-8f / 127.0f);

    dim3 grid(O / 128, M / 256);   // (16, 64) = 1024 blocks, %8 == 0
    gemm_i8_fat<<<grid, 256, 0, stream>>>(xq, wqp, xs, wsc, bias, out, D);
}